// Round 1
// baseline (646.235 us; speedup 1.0000x reference)
//
#include <hip/hip_runtime.h>

#define BB 64
#define DD 768
#define MM 2048
#define CC 1000
#define NEG 0.01f
#define ECH 8
#define EPER (DD / ECH) // 96

// ---------------------------------------------------------------------------
// Kernel A: out[r,c] = sum_k A[r,k] * W[k,c]   for A [64,768], W [768,768]
// grid (64, 3), block 256. A-row staged in LDS; W reads coalesced over c.
// ---------------------------------------------------------------------------
__global__ __launch_bounds__(256) void gemm64(const float* __restrict__ A,
                                              const float* __restrict__ W,
                                              float* __restrict__ out) {
    __shared__ float as[DD];
    const int r = blockIdx.x;
    const int c = blockIdx.y * 256 + threadIdx.x;
    for (int k = threadIdx.x; k < DD; k += 256) as[k] = A[r * DD + k];
    __syncthreads();
    float acc = 0.f;
#pragma unroll 8
    for (int k = 0; k < DD; ++k) acc = fmaf(as[k], W[k * DD + c], acc);
    out[r * DD + c] = acc;
}

// ---------------------------------------------------------------------------
// Kernel B: partial[b,ec,m] = sum_{e in chunk ec} q2[b,e] * mem[b,e,m]
// grid (64, 8), block 512. Each thread owns one float4 of m (512*4 = 2048).
// mem rows are contiguous in m -> perfectly coalesced 16B/lane loads.
// ---------------------------------------------------------------------------
__global__ __launch_bounds__(512) void scores_partial(const float* __restrict__ mem,
                                                      const float* __restrict__ q2,
                                                      float* __restrict__ part) {
    const int b = blockIdx.x;
    const int ec = blockIdx.y;
    const int e0 = ec * EPER;
    __shared__ float qs[EPER];
    if (threadIdx.x < EPER) qs[threadIdx.x] = q2[b * DD + e0 + threadIdx.x];
    __syncthreads();

    const float4* mp = (const float4*)(mem + ((size_t)b * DD + e0) * MM);
    const int m4 = threadIdx.x; // 0..511
    float4 acc = {0.f, 0.f, 0.f, 0.f};
#pragma unroll 4
    for (int e = 0; e < EPER; ++e) {
        const float q = qs[e];
        const float4 v = mp[(size_t)e * (MM / 4) + m4];
        acc.x = fmaf(q, v.x, acc.x);
        acc.y = fmaf(q, v.y, acc.y);
        acc.z = fmaf(q, v.z, acc.z);
        acc.w = fmaf(q, v.w, acc.w);
    }
    ((float4*)(part + ((size_t)b * ECH + ec) * MM))[m4] = acc;
}

// ---------------------------------------------------------------------------
// Kernel C: per-b finalize — sum partials, leaky relu, scatter-add into
// class bins (LDS atomics), max-subtracted softmax, write out.
// grid 64, block 256.
// ---------------------------------------------------------------------------
__global__ __launch_bounds__(256) void finalize(const float* __restrict__ part,
                                                const int* __restrict__ labels,
                                                float* __restrict__ out) {
    __shared__ float logits[CC];
    __shared__ float red[16];
    const int b = blockIdx.x;

    for (int i = threadIdx.x; i < CC; i += 256) logits[i] = 0.f;
    __syncthreads();

    for (int m = threadIdx.x; m < MM; m += 256) {
        float s = 0.f;
#pragma unroll
        for (int ec = 0; ec < ECH; ++ec)
            s += part[((size_t)b * ECH + ec) * MM + m];
        s = (s >= 0.f) ? s : NEG * s;
        const int lab = labels[b * MM + m];
        atomicAdd(&logits[lab], s);
    }
    __syncthreads();

    // row max
    float mx = -INFINITY;
    for (int i = threadIdx.x; i < CC; i += 256) mx = fmaxf(mx, logits[i]);
#pragma unroll
    for (int o = 1; o < 64; o <<= 1) mx = fmaxf(mx, __shfl_xor(mx, o, 64));
    const int wid = threadIdx.x >> 6;
    if ((threadIdx.x & 63) == 0) red[wid] = mx;
    __syncthreads();
    mx = fmaxf(fmaxf(red[0], red[1]), fmaxf(red[2], red[3]));

    // sum of exp
    float sm = 0.f;
    for (int i = threadIdx.x; i < CC; i += 256) sm += expf(logits[i] - mx);
#pragma unroll
    for (int o = 1; o < 64; o <<= 1) sm += __shfl_xor(sm, o, 64);
    if ((threadIdx.x & 63) == 0) red[8 + wid] = sm;
    __syncthreads();
    sm = red[8] + red[9] + red[10] + red[11];

    const float inv = 1.f / sm;
    for (int i = threadIdx.x; i < CC; i += 256)
        out[b * CC + i] = expf(logits[i] - mx) * inv;
}

extern "C" void kernel_launch(void* const* d_in, const int* in_sizes, int n_in,
                              void* d_out, int out_size, void* d_ws, size_t ws_size,
                              hipStream_t stream) {
    const float* x      = (const float*)d_in[0]; // [B, D]
    const float* mem    = (const float*)d_in[1]; // [B, D, M]
    const int*   labels = (const int*)d_in[2];   // [B, M]
    const float* W_Q    = (const float*)d_in[3]; // [D, D]
    const float* W_K    = (const float*)d_in[4]; // [D, D]
    float* out = (float*)d_out;                  // [B, C]

    float* ws   = (float*)d_ws;
    float* q1   = ws;                  // B*D
    float* q2   = ws + BB * DD;        // B*D
    float* part = ws + 2 * BB * DD;    // B*ECH*M

    // q1 = x @ W_K ; q2 = q1 @ W_Q
    gemm64<<<dim3(BB, DD / 256), 256, 0, stream>>>(x, W_K, q1);
    gemm64<<<dim3(BB, DD / 256), 256, 0, stream>>>(q1, W_Q, q2);
    // partial scores over e-chunks
    scores_partial<<<dim3(BB, ECH), 512, 0, stream>>>(mem, q2, part);
    // sum + leaky relu + scatter + softmax
    finalize<<<BB, 256, 0, stream>>>(part, labels, out);
}

// Round 4
// 617.692 us; speedup vs baseline: 1.0462x; 1.0462x over previous
//
#include <hip/hip_runtime.h>

#define BB 64
#define DD 768
#define MM 2048
#define CC 1000
#define NEG 0.01f

// ---------------------------------------------------------------------------
// K1/K2: out[r,c] = sum_d A[r,d] * W[d,c]  (A [64,768], W [768,768])
// One output per thread; grid 96 x 512 = 49152 threads. W reads coalesced
// over c; A reads are wave-uniform broadcasts. Optionally zeroes a buffer
// (used by K2 to clear the logits accumulator, since ws is poisoned 0xAA).
// ---------------------------------------------------------------------------
__global__ __launch_bounds__(512) void rowgemm_k(const float* __restrict__ A,
                                                 const float* __restrict__ W,
                                                 float* __restrict__ out,
                                                 float* __restrict__ zero_buf,
                                                 int zero_n) {
    const int gt = blockIdx.x * 512 + threadIdx.x; // 0..49151
    const int r = gt / DD;
    const int c = gt - r * DD;
    const float* a = A + r * DD;
    const float* w = W + c;
    float acc0 = 0.f, acc1 = 0.f;
#pragma unroll 8
    for (int d = 0; d < DD; d += 2) {
        acc0 = fmaf(a[d], w[(size_t)d * DD], acc0);
        acc1 = fmaf(a[d + 1], w[(size_t)(d + 1) * DD], acc1);
    }
    out[gt] = acc0 + acc1;
    if (zero_buf != nullptr) {
        for (int i = gt; i < zero_n; i += 96 * 512) zero_buf[i] = 0.f;
    }
}

// ---------------------------------------------------------------------------
// K3: fused scores + leaky-relu + scatter.
// grid (64 b, 4 mt), 512 threads; thread owns one m = mt*512+tid.
// Streams mem[b, :, m] (stride-MM loads, per-wave 256B contiguous), dots with
// q2[b,:] staged in LDS, applies leaky relu, scatters into LDS class bins,
// then one global atomicAdd per touched class into logits_g[b].
// ---------------------------------------------------------------------------
__global__ __launch_bounds__(512) void scores_scatter_k(const float* __restrict__ mem,
                                                        const float* __restrict__ q2,
                                                        const int* __restrict__ labels,
                                                        float* __restrict__ logits_g) {
    const int b = blockIdx.x;
    const int m = blockIdx.y * 512 + threadIdx.x;
    __shared__ float qs[DD];
    __shared__ float lg[CC];
    for (int i = threadIdx.x; i < DD; i += 512) qs[i] = q2[b * DD + i];
    for (int i = threadIdx.x; i < CC; i += 512) lg[i] = 0.f;
    __syncthreads();

    const float* mp = mem + (size_t)b * DD * MM + m;
    float acc = 0.f;
#pragma unroll 16
    for (int e = 0; e < DD; ++e)
        acc = fmaf(qs[e], mp[(size_t)e * MM], acc);

    acc = (acc >= 0.f) ? acc : NEG * acc;
    atomicAdd(&lg[labels[b * MM + m]], acc);
    __syncthreads();

    for (int i = threadIdx.x; i < CC; i += 512)
        if (lg[i] != 0.f) atomicAdd(&logits_g[b * CC + i], lg[i]);
}

// ---------------------------------------------------------------------------
// K4: per-b softmax over 1000 classes. 64 blocks x 256 threads.
// ---------------------------------------------------------------------------
__global__ __launch_bounds__(256) void softmax_k(const float* __restrict__ lg,
                                                 float* __restrict__ out) {
    const int b = blockIdx.x;
    const int tid = threadIdx.x;
    __shared__ float red[8];
    const int base = b * CC;

    float v0 = lg[base + tid];
    float v1 = lg[base + tid + 256];
    float v2 = lg[base + tid + 512];
    float v3 = (tid < CC - 768) ? lg[base + tid + 768] : -INFINITY;

    float mx = fmaxf(fmaxf(v0, v1), fmaxf(v2, v3));
#pragma unroll
    for (int o = 1; o < 64; o <<= 1) mx = fmaxf(mx, __shfl_xor(mx, o, 64));
    if ((tid & 63) == 0) red[tid >> 6] = mx;
    __syncthreads();
    mx = fmaxf(fmaxf(red[0], red[1]), fmaxf(red[2], red[3]));

    v0 = expf(v0 - mx);
    v1 = expf(v1 - mx);
    v2 = expf(v2 - mx);
    v3 = (tid < CC - 768) ? expf(v3 - mx) : 0.f;
    float sm = v0 + v1 + v2 + v3;
#pragma unroll
    for (int o = 1; o < 64; o <<= 1) sm += __shfl_xor(sm, o, 64);
    if ((tid & 63) == 0) red[4 + (tid >> 6)] = sm;
    __syncthreads();
    const float inv = 1.f / (red[4] + red[5] + red[6] + red[7]);

    out[base + tid] = v0 * inv;
    out[base + tid + 256] = v1 * inv;
    out[base + tid + 512] = v2 * inv;
    if (tid < CC - 768) out[base + tid + 768] = v3 * inv;
}

extern "C" void kernel_launch(void* const* d_in, const int* in_sizes, int n_in,
                              void* d_out, int out_size, void* d_ws, size_t ws_size,
                              hipStream_t stream) {
    const float* x      = (const float*)d_in[0]; // [B, D]
    const float* mem    = (const float*)d_in[1]; // [B, D, M]
    const int*   labels = (const int*)d_in[2];   // [B, M]
    const float* W_Q    = (const float*)d_in[3]; // [D, D]
    const float* W_K    = (const float*)d_in[4]; // [D, D]
    float* out = (float*)d_out;                  // [B, C]

    float* ws       = (float*)d_ws;
    float* q1       = ws;                     // B*D
    float* q2       = ws + BB * DD;           // B*D
    float* logits_g = ws + 2 * BB * DD;       // B*C

    // q1 = x @ W_K
    rowgemm_k<<<96, 512, 0, stream>>>(x, W_K, q1, nullptr, 0);
    // q2 = q1 @ W_Q; also zero the logits accumulator (ws is poisoned)
    rowgemm_k<<<96, 512, 0, stream>>>(q1, W_Q, q2, logits_g, BB * CC);
    // fused scores + leaky relu + scatter
    scores_scatter_k<<<dim3(BB, MM / 512), 512, 0, stream>>>(mem, q2, labels, logits_g);
    // softmax
    softmax_k<<<BB, 256, 0, stream>>>(logits_g, out);
}

// Round 6
// 606.687 us; speedup vs baseline: 1.0652x; 1.0181x over previous
//
#include <hip/hip_runtime.h>

#define BB 64
#define DD 768
#define MM 2048
#define CC 1000
#define NEG 0.01f

// ---------------------------------------------------------------------------
// K1/K2: out[r,c] = sum_d A[r,d] * W[d,c]  (A [64,768], W [768,768])
// grid 192 x 256 (256 divides 768 -> r is block-uniform, A reads are scalar
// broadcasts). W reads coalesced over c (256B/wave-instr, L2-resident).
// Optionally zeroes a buffer (K2 clears the logits accumulator; ws is 0xAA).
// ---------------------------------------------------------------------------
__global__ __launch_bounds__(256) void rowgemm_k(const float* __restrict__ A,
                                                 const float* __restrict__ W,
                                                 float* __restrict__ out,
                                                 float* __restrict__ zero_buf,
                                                 int zero_n) {
    const int gt = blockIdx.x * 256 + threadIdx.x; // 0..49151
    const int r = gt / DD;
    const int c = gt - r * DD;
    const float* a = A + r * DD;
    const float* w = W + c;
    float acc0 = 0.f, acc1 = 0.f;
#pragma unroll 8
    for (int d = 0; d < DD; d += 2) {
        acc0 = fmaf(a[d], w[(size_t)d * DD], acc0);
        acc1 = fmaf(a[d + 1], w[(size_t)(d + 1) * DD], acc1);
    }
    out[gt] = acc0 + acc1;
    if (zero_buf != nullptr) {
        for (int i = gt; i < zero_n; i += 192 * 256) zero_buf[i] = 0.f;
    }
}

// ---------------------------------------------------------------------------
// K3: fused scores + leaky-relu + scatter, float4 edition.
// grid (64 b, 4 mt), block 512 = 4 e-subsets x 128 m-quads; m-tile = 512 m.
// Each thread accumulates float4 over e = es, es+4, ... (192 iters of 16B
// loads; 1KB contiguous per wave-instr). Partials reduced over e-subsets in
// LDS, then leaky-relu + LDS class-bin scatter + one global atomicAdd per
// touched class.
// ---------------------------------------------------------------------------
__global__ __launch_bounds__(512) void scores_scatter_k(const float* __restrict__ mem,
                                                        const float* __restrict__ q2,
                                                        const int* __restrict__ labels,
                                                        float* __restrict__ logits_g) {
    const int b = blockIdx.x;
    const int mbase = blockIdx.y * 512;
    const int es = threadIdx.x >> 7;   // 0..3
    const int m4 = threadIdx.x & 127;  // 0..127

    __shared__ float qs[DD];
    __shared__ float lg[CC];
    __shared__ float4 sm[512];

    for (int i = threadIdx.x; i < DD; i += 512) qs[i] = q2[b * DD + i];
    for (int i = threadIdx.x; i < CC; i += 512) lg[i] = 0.f;
    __syncthreads();

    const float4* mp = (const float4*)(mem + (size_t)b * DD * MM + mbase);
    float4 acc = {0.f, 0.f, 0.f, 0.f};
#pragma unroll 8
    for (int e = es; e < DD; e += 4) {
        const float q = qs[e];
        const float4 v = mp[(size_t)e * (MM / 4) + m4];
        acc.x = fmaf(q, v.x, acc.x);
        acc.y = fmaf(q, v.y, acc.y);
        acc.z = fmaf(q, v.z, acc.z);
        acc.w = fmaf(q, v.w, acc.w);
    }
    sm[threadIdx.x] = acc;
    __syncthreads();

    if (threadIdx.x < 128) {
        const float4 a0 = sm[threadIdx.x];
        const float4 a1 = sm[threadIdx.x + 128];
        const float4 a2 = sm[threadIdx.x + 256];
        const float4 a3 = sm[threadIdx.x + 384];
        float s0 = a0.x + a1.x + a2.x + a3.x;
        float s1 = a0.y + a1.y + a2.y + a3.y;
        float s2 = a0.z + a1.z + a2.z + a3.z;
        float s3 = a0.w + a1.w + a2.w + a3.w;
        s0 = (s0 >= 0.f) ? s0 : NEG * s0;
        s1 = (s1 >= 0.f) ? s1 : NEG * s1;
        s2 = (s2 >= 0.f) ? s2 : NEG * s2;
        s3 = (s3 >= 0.f) ? s3 : NEG * s3;
        const int4 lab = ((const int4*)(labels + b * MM + mbase))[threadIdx.x];
        atomicAdd(&lg[lab.x], s0);
        atomicAdd(&lg[lab.y], s1);
        atomicAdd(&lg[lab.z], s2);
        atomicAdd(&lg[lab.w], s3);
    }
    __syncthreads();

    for (int i = threadIdx.x; i < CC; i += 512)
        if (lg[i] != 0.f) atomicAdd(&logits_g[b * CC + i], lg[i]);
}

// ---------------------------------------------------------------------------
// K4: per-b softmax over 1000 classes. 64 blocks x 256 threads.
// ---------------------------------------------------------------------------
__global__ __launch_bounds__(256) void softmax_k(const float* __restrict__ lg,
                                                 float* __restrict__ out) {
    const int b = blockIdx.x;
    const int tid = threadIdx.x;
    __shared__ float red[8];
    const int base = b * CC;

    float v0 = lg[base + tid];
    float v1 = lg[base + tid + 256];
    float v2 = lg[base + tid + 512];
    float v3 = (tid < CC - 768) ? lg[base + tid + 768] : -INFINITY;

    float mx = fmaxf(fmaxf(v0, v1), fmaxf(v2, v3));
#pragma unroll
    for (int o = 1; o < 64; o <<= 1) mx = fmaxf(mx, __shfl_xor(mx, o, 64));
    if ((tid & 63) == 0) red[tid >> 6] = mx;
    __syncthreads();
    mx = fmaxf(fmaxf(red[0], red[1]), fmaxf(red[2], red[3]));

    v0 = expf(v0 - mx);
    v1 = expf(v1 - mx);
    v2 = expf(v2 - mx);
    v3 = (tid < CC - 768) ? expf(v3 - mx) : 0.f;
    float sm = v0 + v1 + v2 + v3;
#pragma unroll
    for (int o = 1; o < 64; o <<= 1) sm += __shfl_xor(sm, o, 64);
    if ((tid & 63) == 0) red[4 + (tid >> 6)] = sm;
    __syncthreads();
    const float inv = 1.f / (red[4] + red[5] + red[6] + red[7]);

    out[base + tid] = v0 * inv;
    out[base + tid + 256] = v1 * inv;
    out[base + tid + 512] = v2 * inv;
    if (tid < CC - 768) out[base + tid + 768] = v3 * inv;
}

extern "C" void kernel_launch(void* const* d_in, const int* in_sizes, int n_in,
                              void* d_out, int out_size, void* d_ws, size_t ws_size,
                              hipStream_t stream) {
    const float* x      = (const float*)d_in[0]; // [B, D]
    const float* mem    = (const float*)d_in[1]; // [B, D, M]
    const int*   labels = (const int*)d_in[2];   // [B, M]
    const float* W_Q    = (const float*)d_in[3]; // [D, D]
    const float* W_K    = (const float*)d_in[4]; // [D, D]
    float* out = (float*)d_out;                  // [B, C]

    float* ws       = (float*)d_ws;
    float* q1       = ws;                     // B*D
    float* q2       = ws + BB * DD;           // B*D
    float* logits_g = ws + 2 * BB * DD;       // B*C

    // q1 = x @ W_K
    rowgemm_k<<<192, 256, 0, stream>>>(x, W_K, q1, nullptr, 0);
    // q2 = q1 @ W_Q; also zero the logits accumulator (ws is poisoned)
    rowgemm_k<<<192, 256, 0, stream>>>(q1, W_Q, q2, logits_g, BB * CC);
    // fused scores + leaky relu + scatter (float4 streaming)
    scores_scatter_k<<<dim3(BB, MM / 512), 512, 0, stream>>>(mem, q2, labels, logits_g);
    // softmax
    softmax_k<<<BB, 256, 0, stream>>>(logits_g, out);
}